// Round 7
// baseline (254.183 us; speedup 1.0000x reference)
//
#include <hip/hip_runtime.h>
#include <cstddef>

#define E 512
#define H 8
#define D 64
#define BATCH 2
#define SEQ 4096

typedef __attribute__((ext_vector_type(8))) short bf16x8;  // MFMA A/B frag
typedef __attribute__((ext_vector_type(4))) float f32x4;   // MFMA C/D frag

__device__ __forceinline__ ushort f2bf(float f) {
  unsigned u = __builtin_bit_cast(unsigned, f);
  u += 0x7fff + ((u >> 16) & 1);  // RNE
  return (ushort)(u >> 16);
}
__device__ __forceinline__ float bf2f(ushort h) {
  return __builtin_bit_cast(float, (unsigned)h << 16);
}
__device__ __forceinline__ unsigned pk_bf16(float lo, float hi) {
#if __has_builtin(__builtin_amdgcn_cvt_pk_bf16_f32)
  typedef __attribute__((ext_vector_type(2))) __bf16 bfv2;
  bfv2 r = __builtin_amdgcn_cvt_pk_bf16_f32(lo, hi);
  return __builtin_bit_cast(unsigned, r);
#else
  return (unsigned)f2bf(lo) | ((unsigned)f2bf(hi) << 16);
#endif
}
__device__ __forceinline__ float fexp2(float x) {
#if __has_builtin(__builtin_amdgcn_exp2f)
  return __builtin_amdgcn_exp2f(x);
#else
  return exp2f(x);
#endif
}

// ---------------------------------------------------------------------------
// Kernel 0: cast x -> bf16 hi/lo split (xh + xl ~= x to ~16 mantissa bits)
// ---------------------------------------------------------------------------
__global__ __launch_bounds__(256) void xcast(const float* __restrict__ x,
                                             ushort* __restrict__ xh,
                                             ushort* __restrict__ xl) {
  size_t i = ((size_t)blockIdx.x * 256 + threadIdx.x) * 4;
  float4 v = *(const float4*)&x[i];
  ushort4 h, l;
  h.x = f2bf(v.x); l.x = f2bf(v.x - bf2f(h.x));
  h.y = f2bf(v.y); l.y = f2bf(v.y - bf2f(h.y));
  h.z = f2bf(v.z); l.z = f2bf(v.z - bf2f(h.z));
  h.w = f2bf(v.w); l.w = f2bf(v.w - bf2f(h.w));
  *(ushort4*)&xh[i] = h;
  *(ushort4*)&xl[i] = l;
}

// ---------------------------------------------------------------------------
// Kernel 1a: fold weights. Block = 256 k-lanes x 8 n (8 fp32 accs).
// j unrolled by 16 with all 16 w-loads issued up-front.
// ---------------------------------------------------------------------------
__global__ __launch_bounds__(256) void fold_tiled(
    const float* __restrict__ wq, const float* __restrict__ wk,
    const float* __restrict__ rot, const float* __restrict__ ent,
    ushort* __restrict__ weffbT) {
  const int which = blockIdx.z;
  const float* w = which ? wk : wq;
  const float* r = which ? ent : rot;
  const int k = blockIdx.x * 256 + threadIdx.x;
  const int n0 = blockIdx.y * 8;
  float acc[8] = {};
  for (int j0 = 0; j0 < E; j0 += 16) {
    float wv_[16];
#pragma unroll
    for (int u = 0; u < 16; ++u) wv_[u] = w[(size_t)(j0 + u) * E + k];
#pragma unroll
    for (int u = 0; u < 16; ++u)
#pragma unroll
      for (int t = 0; t < 8; ++t)
        acc[t] += wv_[u] * r[(size_t)(j0 + u) * E + n0 + t];
  }
#pragma unroll
  for (int t = 0; t < 8; ++t)
    weffbT[(size_t)which * E * E + (size_t)(n0 + t) * E + k] = f2bf(acc[t]);
}

// Kernel 1b: weffT[2][n][k] = bf16(wv[n][k]) — identity layout, pure cast.
__global__ __launch_bounds__(256) void wv_cast(const float* __restrict__ wv,
                                               ushort* __restrict__ dst) {
  size_t i = ((size_t)blockIdx.x * 256 + threadIdx.x) * 4;
  float4 v = *(const float4*)&wv[i];
  ushort4 o;
  o.x = f2bf(v.x); o.y = f2bf(v.y); o.z = f2bf(v.z); o.w = f2bf(v.w);
  *(ushort4*)&dst[i] = o;
}

// ---------------------------------------------------------------------------
// Kernel 2: QKV GEMM v2. One block = (head, 128 m-rows) x ALL 192 out-cols
// (q|k|v for that head): A (xh+xl) is read from HBM exactly ONCE (was x8).
// A staged in LDS (20.5 KB); B-fragments load DIRECTLY from global (weffbT
// is 768 KB bf16 -> L2-resident on every XCD) with 1-iter register prefetch:
// no B staging, no second LDS stream, 24 MFMA per wave per 32-k step.
// 8 waves = 2 m-groups(64) x 4 n-groups(48 cols = 3 ntiles). Every 16-col
// tile lies in exactly one w ((48g+16nt) mod 64 in {0,16,32,48}).
// ---------------------------------------------------------------------------
#define LDA 40  // padded LDS stride (bf16): 80B

__global__ __launch_bounds__(512) void qkv_v2(
    const ushort* __restrict__ xhg, const ushort* __restrict__ xlg,
    const ushort* __restrict__ weffbT, ushort* __restrict__ qg,
    ushort* __restrict__ kg, ushort* __restrict__ vtg) {
  __shared__ ushort sm[2 * 128 * LDA];  // Ah | Al ; reused as vt in epilogue
  ushort* Ah = sm;
  ushort* Al = sm + 128 * LDA;

  const int head = blockIdx.x;
  const int m0 = blockIdx.y * 128;
  const int tid = threadIdx.x;
  const int wave = tid >> 6, lane = tid & 63;
  const int l15 = lane & 15, quad = lane >> 4;
  const int mg = wave >> 2, ng = wave & 3;

  const int arow = tid >> 2, ak8 = (tid & 3) * 8;  // A staging slot (128x32)
  const ushort* aptr_h = xhg + (size_t)(m0 + arow) * E + ak8;
  const ushort* aptr_l = xlg + (size_t)(m0 + arow) * E + ak8;

  // B fragment base pointers (global, k-major rows of weffbT)
  const ushort* bptr[3];
#pragma unroll
  for (int nt = 0; nt < 3; ++nt) {
    int rb = ng * 48 + nt * 16 + l15;  // 0..191 across the 3 weights
    bptr[nt] = weffbT +
               ((size_t)(rb >> 6) * E + head * 64 + (rb & 63)) * E + quad * 8;
  }

  f32x4 acc[4][3];
#pragma unroll
  for (int ms = 0; ms < 4; ++ms)
#pragma unroll
    for (int nt = 0; nt < 3; ++nt) acc[ms][nt] = (f32x4){0.f, 0.f, 0.f, 0.f};

  // preload k0 = 0
  uint4 pa_h = *(const uint4*)aptr_h;
  uint4 pa_l = *(const uint4*)aptr_l;
  bf16x8 bf0 = *(const bf16x8*)(bptr[0]);
  bf16x8 bf1 = *(const bf16x8*)(bptr[1]);
  bf16x8 bf2 = *(const bf16x8*)(bptr[2]);

  for (int k0 = 0; k0 < E; k0 += 32) {
    __syncthreads();  // prev iter's A-frag reads done
    *(uint4*)&Ah[arow * LDA + ak8] = pa_h;
    *(uint4*)&Al[arow * LDA + ak8] = pa_l;
    __syncthreads();

    // prefetch next tile (A staging regs + B frags) — hides global latency
    const int kn = (k0 + 32 < E) ? k0 + 32 : 0;
    pa_h = *(const uint4*)(aptr_h + kn);
    pa_l = *(const uint4*)(aptr_l + kn);
    bf16x8 nb0 = *(const bf16x8*)(bptr[0] + kn);
    bf16x8 nb1 = *(const bf16x8*)(bptr[1] + kn);
    bf16x8 nb2 = *(const bf16x8*)(bptr[2] + kn);

    // A fragments from LDS; hi then lo to limit live VGPRs
    bf16x8 ah[4];
#pragma unroll
    for (int ms = 0; ms < 4; ++ms)
      ah[ms] = *(const bf16x8*)&Ah[(mg * 64 + ms * 16 + l15) * LDA + quad * 8];
#pragma unroll
    for (int ms = 0; ms < 4; ++ms) {
      acc[ms][0] =
          __builtin_amdgcn_mfma_f32_16x16x32_bf16(ah[ms], bf0, acc[ms][0], 0, 0, 0);
      acc[ms][1] =
          __builtin_amdgcn_mfma_f32_16x16x32_bf16(ah[ms], bf1, acc[ms][1], 0, 0, 0);
      acc[ms][2] =
          __builtin_amdgcn_mfma_f32_16x16x32_bf16(ah[ms], bf2, acc[ms][2], 0, 0, 0);
    }
    bf16x8 al[4];
#pragma unroll
    for (int ms = 0; ms < 4; ++ms)
      al[ms] = *(const bf16x8*)&Al[(mg * 64 + ms * 16 + l15) * LDA + quad * 8];
#pragma unroll
    for (int ms = 0; ms < 4; ++ms) {
      acc[ms][0] =
          __builtin_amdgcn_mfma_f32_16x16x32_bf16(al[ms], bf0, acc[ms][0], 0, 0, 0);
      acc[ms][1] =
          __builtin_amdgcn_mfma_f32_16x16x32_bf16(al[ms], bf1, acc[ms][1], 0, 0, 0);
      acc[ms][2] =
          __builtin_amdgcn_mfma_f32_16x16x32_bf16(al[ms], bf2, acc[ms][2], 0, 0, 0);
    }
    bf0 = nb0; bf1 = nb1; bf2 = nb2;
  }

  const int b = m0 >> 12;
  const int s_base = m0 & (SEQ - 1);
  const float QSCALE = 0.125f * 1.44269504f;  // fold 1/sqrt(D)*log2(e) into q

  __syncthreads();        // all A-frag reads done before LDS reuse
  ushort* vt = sm;        // v transpose tile: [64 d][128 m], stride 136

#pragma unroll
  for (int nt = 0; nt < 3; ++nt) {
    const int cbase = ng * 48 + nt * 16;  // wave-uniform
    const int w = cbase >> 6;             // 0=q, 1=k, 2=v
    const int dbase = cbase & 63;
    if (w < 2) {
      ushort* dst = (w == 0) ? qg : kg;
      float sc = (w == 0) ? QSCALE : 1.0f;
#pragma unroll
      for (int ms = 0; ms < 4; ++ms)
#pragma unroll
        for (int r = 0; r < 4; ++r) {
          float v = acc[ms][nt][r] * sc;
          float vo = __shfl_xor(v, 1);
          if (!(lane & 1)) {
            int s = s_base + mg * 64 + ms * 16 + quad * 4 + r;
            size_t ix =
                ((size_t)(b * H + head) * SEQ + s) * D + dbase + l15;
            *(unsigned*)&dst[ix] = pk_bf16(v, vo);
          }
        }
    } else {
#pragma unroll
      for (int ms = 0; ms < 4; ++ms) {
        uint2 w2;
        w2.x = pk_bf16(acc[ms][nt][0], acc[ms][nt][1]);
        w2.y = pk_bf16(acc[ms][nt][2], acc[ms][nt][3]);
        *(uint2*)&vt[(dbase + l15) * 136 + mg * 64 + ms * 16 + quad * 4] = w2;
      }
    }
  }
  __syncthreads();
  {
    int d = tid >> 3, mseg = (tid & 7) * 16;
    uint4 c0 = *(const uint4*)&vt[d * 136 + mseg];
    uint4 c1 = *(const uint4*)&vt[d * 136 + mseg + 8];
    size_t vo_ = ((size_t)(b * H + head) * D + d) * SEQ + s_base + mseg;
    *(uint4*)&vtg[vo_] = c0;
    *(uint4*)&vtg[vo_ + 8] = c1;
  }
}

// ---------------------------------------------------------------------------
// Kernel 3: flash attention, transposed-S MFMA, max-free softmax, in-block
// K-split (2 groups x 4 waves). UNCHANGED from round 5/6 (proven 110 us).
// ---------------------------------------------------------------------------
#define LDK 72  // padded stride (bf16): 144B, 16B-aligned

__global__ __launch_bounds__(512, 4) void attn_mfma(
    const ushort* __restrict__ qg, const ushort* __restrict__ kg,
    const ushort* __restrict__ vtg, float* __restrict__ out) {
  __shared__ ushort Ks[2][64 * LDK];   // per-group K tile [kcol][d]
  __shared__ ushort Vs[2][64 * LDK];   // per-group Vt tile [d][kcol]
  __shared__ ushort Ps[8 * 32 * LDK];  // P per wave [wave][32 q][kcol]
  __shared__ float lex[128];

  const int qt = blockIdx.x;  // 0..31 (128 q-rows each)
  const int bh = blockIdx.y;
  const int tid = threadIdx.x;
  const int wave = tid >> 6;  // 0..7
  const int grp = wave >> 2, wq = wave & 3;
  const int lane = tid & 63;
  const int l15 = lane & 15, quad = lane >> 4;
  const int gtid = tid & 255;  // tid within group

  const ushort* qp = qg + (size_t)bh * SEQ * D;
  const ushort* kp = kg + (size_t)bh * SEQ * D;
  const ushort* vp = vtg + (size_t)bh * D * SEQ;
  ushort* Psw = Ps + wave * 32 * LDK;
  ushort* Ksg = Ks[grp];
  ushort* Vsg = Vs[grp];

  const int qrow0 = qt * 128 + wq * 32;
  bf16x8 qf[2][2];  // [sub][ks]: B-operand layout (q=l15, d=ks*32+quad*8+j)
#pragma unroll
  for (int sub = 0; sub < 2; ++sub)
#pragma unroll
    for (int ks = 0; ks < 2; ++ks)
      qf[sub][ks] = *(const bf16x8*)&qp[(size_t)(qrow0 + sub * 16 + l15) * D +
                                        ks * 32 + quad * 8];

  f32x4 o[2][4];
#pragma unroll
  for (int sub = 0; sub < 2; ++sub)
#pragma unroll
    for (int nt = 0; nt < 4; ++nt) o[sub][nt] = (f32x4){0.f, 0.f, 0.f, 0.f};
  float l_r[2] = {0.f, 0.f};  // per-lane partial row-sums (q = l15)

  const int r0 = gtid >> 3, c0 = (gtid & 7) * 8;  // group staging slots
  const int r1 = 32 + r0;

  // preload tile it=0 (kt = grp)
  uint4 pk0 = *(const uint4*)&kp[(size_t)grp * 64 * D + r0 * 64 + c0];
  uint4 pk1 = *(const uint4*)&kp[(size_t)grp * 64 * D + r1 * 64 + c0];
  uint4 pv0 = *(const uint4*)&vp[(size_t)r0 * SEQ + grp * 64 + c0];
  uint4 pv1 = *(const uint4*)&vp[(size_t)r1 * SEQ + grp * 64 + c0];

  for (int it = 0; it < SEQ / 128; ++it) {
    __syncthreads();  // prev iter's frag reads done (both groups)
    *(uint4*)&Ksg[r0 * LDK + c0] = pk0;
    *(uint4*)&Ksg[r1 * LDK + c0] = pk1;
    *(uint4*)&Vsg[r0 * LDK + c0] = pv0;
    *(uint4*)&Vsg[r1 * LDK + c0] = pv1;
    __syncthreads();

    // issue NEXT tile's loads; latency hides under this tile's compute
    {
      const int itn = (it + 1 < SEQ / 128) ? it + 1 : it;
      const int ktn = itn * 2 + grp;
      const ushort* ksrc = kp + (size_t)ktn * 64 * D;
      pk0 = *(const uint4*)&ksrc[r0 * 64 + c0];
      pk1 = *(const uint4*)&ksrc[r1 * 64 + c0];
      pv0 = *(const uint4*)&vp[(size_t)r0 * SEQ + ktn * 64 + c0];
      pv1 = *(const uint4*)&vp[(size_t)r1 * SEQ + ktn * 64 + c0];
    }

    // S^T = K Q^T: K frags read ONCE, shared by both q-subtiles
    f32x4 st[2][4];
#pragma unroll
    for (int sub = 0; sub < 2; ++sub)
#pragma unroll
      for (int knt = 0; knt < 4; ++knt)
        st[sub][knt] = (f32x4){0.f, 0.f, 0.f, 0.f};
#pragma unroll
    for (int knt = 0; knt < 4; ++knt)
#pragma unroll
      for (int ks = 0; ks < 2; ++ks) {
        bf16x8 kf =
            *(const bf16x8*)&Ksg[(knt * 16 + l15) * LDK + ks * 32 + quad * 8];
        st[0][knt] = __builtin_amdgcn_mfma_f32_16x16x32_bf16(
            kf, qf[0][ks], st[0][knt], 0, 0, 0);
        st[1][knt] = __builtin_amdgcn_mfma_f32_16x16x32_bf16(
            kf, qf[1][ks], st[1][knt], 0, 0, 0);
      }

    // max-free softmax: p = exp2(score), per-lane running sum, pack to LDS
#pragma unroll
    for (int sub = 0; sub < 2; ++sub) {
      float rs = 0.f;
#pragma unroll
      for (int knt = 0; knt < 4; ++knt) {
        float p0 = fexp2(st[sub][knt][0]);
        float p1 = fexp2(st[sub][knt][1]);
        float p2 = fexp2(st[sub][knt][2]);
        float p3 = fexp2(st[sub][knt][3]);
        rs += (p0 + p1) + (p2 + p3);
        uint2 w2;
        w2.x = pk_bf16(p0, p1);
        w2.y = pk_bf16(p2, p3);
        *(uint2*)&Psw[(sub * 16 + l15) * LDK + knt * 16 + quad * 4] = w2;
      }
      l_r[sub] += rs;
    }
    __asm__ volatile("s_waitcnt lgkmcnt(0)" ::: "memory");

    // O += P V: V frags read ONCE, shared by both subtiles
    bf16x8 pf[2][2];
#pragma unroll
    for (int sub = 0; sub < 2; ++sub)
#pragma unroll
      for (int ks = 0; ks < 2; ++ks)
        pf[sub][ks] = *(const bf16x8*)&Psw[(sub * 16 + l15) * LDK + ks * 32 +
                                           quad * 8];
#pragma unroll
    for (int nt = 0; nt < 4; ++nt)
#pragma unroll
      for (int ks = 0; ks < 2; ++ks) {
        bf16x8 vf =
            *(const bf16x8*)&Vsg[(nt * 16 + l15) * LDK + ks * 32 + quad * 8];
        o[0][nt] = __builtin_amdgcn_mfma_f32_16x16x32_bf16(pf[0][ks], vf,
                                                           o[0][nt], 0, 0, 0);
        o[1][nt] = __builtin_amdgcn_mfma_f32_16x16x32_bf16(pf[1][ks], vf,
                                                           o[1][nt], 0, 0, 0);
      }
  }

  // ---- combine the two K-halves (additive: no max bookkeeping) ----
  __syncthreads();  // all waves done with Ps before overlay
  float lsum[2];
#pragma unroll
  for (int sub = 0; sub < 2; ++sub) {
    float l = l_r[sub];
    l += __shfl_xor(l, 16);
    l += __shfl_xor(l, 32);
    lsum[sub] = l;  // total for q = l15 over this group's keys
  }
  float* Oex = (float*)Ps;  // [128 q][64 d], stride 68 floats (pad)
  if (grp == 1) {
#pragma unroll
    for (int sub = 0; sub < 2; ++sub)
#pragma unroll
      for (int nt = 0; nt < 4; ++nt)
#pragma unroll
        for (int r = 0; r < 4; ++r)
          Oex[(wq * 32 + sub * 16 + quad * 4 + r) * 68 + nt * 16 + l15] =
              o[sub][nt][r];
    if (quad == 0) {
      lex[wq * 32 + l15] = lsum[0];
      lex[wq * 32 + 16 + l15] = lsum[1];
    }
  }
  __syncthreads();
  if (grp == 0) {
    const int b = bh >> 3, h = bh & 7;
#pragma unroll
    for (int sub = 0; sub < 2; ++sub) {
      float l = lsum[sub] + lex[wq * 32 + sub * 16 + l15];
      float linv = 1.f / l;
      float inv_r[4];
#pragma unroll
      for (int r = 0; r < 4; ++r) inv_r[r] = __shfl(linv, quad * 4 + r);
#pragma unroll
      for (int nt = 0; nt < 4; ++nt)
#pragma unroll
        for (int r = 0; r < 4; ++r) {
          int row = wq * 32 + sub * 16 + quad * 4 + r;
          float val = o[sub][nt][r] + Oex[row * 68 + nt * 16 + l15];
          int srow = qt * 128 + row;
          out[((size_t)b * SEQ + srow) * E + h * D + nt * 16 + l15] =
              val * inv_r[r];
        }
    }
  }
}

// ---------------------------------------------------------------------------
extern "C" void kernel_launch(void* const* d_in, const int* in_sizes, int n_in,
                              void* d_out, int out_size, void* d_ws,
                              size_t ws_size, hipStream_t stream) {
  const float* rot = (const float*)d_in[0];
  const float* ent = (const float*)d_in[1];
  const float* x = (const float*)d_in[2];
  const float* wq = (const float*)d_in[3];
  const float* wk = (const float*)d_in[4];
  const float* wv = (const float*)d_in[5];
  float* out = (float*)d_out;

  const size_t NX = (size_t)BATCH * SEQ * E;  // 4M elements
  ushort* weffbT = (ushort*)d_ws;             // 3*E*E bf16 (1.5 MB)
  ushort* xh = weffbT + 3 * E * E;
  ushort* xl = xh + NX;
  ushort* qg = xl + NX;
  ushort* kg = qg + NX;
  ushort* vtg = kg + NX;

  xcast<<<dim3(NX / 1024), 256, 0, stream>>>(x, xh, xl);
  fold_tiled<<<dim3(E / 256, E / 8, 2), 256, 0, stream>>>(wq, wk, rot, ent,
                                                          weffbT);
  wv_cast<<<dim3(E * E / 1024), 256, 0, stream>>>(wv, weffbT + 2 * E * E);
  qkv_v2<<<dim3(H, BATCH * SEQ / 128), 512, 0, stream>>>(xh, xl, weffbT, qg,
                                                         kg, vtg);
  attn_mfma<<<dim3(SEQ / 128, BATCH * H), 512, 0, stream>>>(qg, kg, vtg, out);
}